// Round 2
// baseline (3522.300 us; speedup 1.0000x reference)
//
#include <hip/hip_runtime.h>
#include <hip/hip_fp16.h>
#include <stdint.h>

#define Bsz 64
#define Tsz 1024
#define Dsz 256
#define UNITSn 256
#define Zdim 1024      // 4*UNITS
// lstm v2: thread (half=tid>>8, u=tid&255) computes half-K partial dots for the
// 4 gate columns {g*256+u} of unit u. Per thread: 16 uint4 of f16-pair W per col's
// half-K (64 k2 pairs); 12 uint4/col live in VGPRs (192 regs), 4 uint4/col stream
// from global (L2-resident, 128 KB total) each step.
#define QV 12
#define QG 4

typedef _Float16 half2v __attribute__((ext_vector_type(2)));

__device__ __forceinline__ float dot2acc(uint32_t w, uint32_t h, float acc) {
#if __has_builtin(__builtin_amdgcn_fdot2)
  return __builtin_amdgcn_fdot2(__builtin_bit_cast(half2v, w),
                                __builtin_bit_cast(half2v, h), acc, false);
#else
  __half2 wv = __builtin_bit_cast(__half2, w);
  __half2 hv = __builtin_bit_cast(__half2, h);
  acc = fmaf(__half2float(__low2half(wv)),  __half2float(__low2half(hv)),  acc);
  acc = fmaf(__half2float(__high2half(wv)), __half2float(__high2half(hv)), acc);
  return acc;
#endif
}

__device__ __forceinline__ float dot4(const uint4& w, const uint4& h, float acc) {
  acc = dot2acc(w.x, h.x, acc); acc = dot2acc(w.y, h.y, acc);
  acc = dot2acc(w.z, h.z, acc); acc = dot2acc(w.w, h.w, acc);
  return acc;
}

__device__ __forceinline__ float sigm(float x)   { return 1.0f / (1.0f + __expf(-x)); }
__device__ __forceinline__ float tanh_f(float x) { return 1.0f - 2.0f / (__expf(2.0f * x) + 1.0f); }

// Repack W[256][1024] fp32 into the lstm thread layout (f16 pairs along k):
//  Wreg[q][t] (q=g*QV+j, j=0..QV-1): k2 = half*64 + j*4 + e, col = g*256+u
//  Wg[j2][t]  (j2=g*QG+jj):          k2 = half*64 + QV*4 + jj*4 + e
__global__ __launch_bounds__(256) void convert_w2(const float* __restrict__ W,
                                                  uint4* __restrict__ Wreg,
                                                  uint4* __restrict__ Wg) {
  int i = blockIdx.x * 256 + threadIdx.x;        // 512*48 + 512*16 = 32768 total
  if (i >= 512 * (QV + QG) * 4) return;
  bool isReg = i < 512 * QV * 4;
  int q, t, k2rel, col;
  if (isReg) {
    q = i >> 9; t = i & 511;
    int g = q / QV, j = q - g * QV;
    k2rel = j * 4;
    col = g * 256 + (t & 255);
  } else {
    int i2 = i - 512 * QV * 4;
    q = i2 >> 9; t = i2 & 511;
    int g = q >> 2, jj = q & 3;
    k2rel = QV * 4 + jj * 4;
    col = g * 256 + (t & 255);
  }
  int half = t >> 8;
  uint32_t d[4];
#pragma unroll
  for (int e = 0; e < 4; e++) {
    int k2 = half * 64 + k2rel + e;
    float w0 = W[(size_t)(2 * k2) * Zdim + col];
    float w1 = W[(size_t)(2 * k2 + 1) * Zdim + col];
    __half2 p = __floats2half2_rn(w0, w1);
    d[e] = __builtin_bit_cast(uint32_t, p);
  }
  uint4 v = make_uint4(d[0], d[1], d[2], d[3]);
  if (isReg) Wreg[(size_t)q * 512 + t] = v;
  else       Wg[(size_t)q * 512 + t] = v;
}

// xz[(tloc*64 + b)*1024 + n] = x[b][t0+tloc][:] @ U[:,n] + bias[n]   (fp32 GEMM)
__global__ __launch_bounds__(256) void proj_gemm(
    const float* __restrict__ x, const float* __restrict__ U,
    const float* __restrict__ bias, float* __restrict__ xz, int t0) {
  __shared__ float At[32][68];
  __shared__ float Bt[32][68];
  const int tid  = threadIdx.x;
  const int n0   = blockIdx.x * 64;
  const int tloc = blockIdx.y;
  const int t    = t0 + tloc;
  const int tm = tid >> 4, tn = tid & 15;
  const int am = tid >> 3, ak = (tid & 7) * 4;
  const int bk = tid >> 4, bn = (tid & 15) * 4;
  const float* xb = x + (size_t)t * Dsz;

  float acc[4][4] = {};
  for (int k0 = 0; k0 < Dsz; k0 += 32) {
    float4 a0 = *(const float4*)(xb + (size_t)am * (Tsz * Dsz) + k0 + ak);
    float4 a1 = *(const float4*)(xb + (size_t)(am + 32) * (Tsz * Dsz) + k0 + ak);
    float4 b0 = *(const float4*)(U + (size_t)(k0 + bk) * Zdim + n0 + bn);
    float4 b1 = *(const float4*)(U + (size_t)(k0 + bk + 16) * Zdim + n0 + bn);
    __syncthreads();
    At[ak + 0][am] = a0.x; At[ak + 1][am] = a0.y; At[ak + 2][am] = a0.z; At[ak + 3][am] = a0.w;
    At[ak + 0][am + 32] = a1.x; At[ak + 1][am + 32] = a1.y; At[ak + 2][am + 32] = a1.z; At[ak + 3][am + 32] = a1.w;
    *(float4*)&Bt[bk][bn]      = b0;
    *(float4*)&Bt[bk + 16][bn] = b1;
    __syncthreads();
#pragma unroll
    for (int kk = 0; kk < 32; kk++) {
      float4 av = *(const float4*)&At[kk][tm * 4];
      float4 bv = *(const float4*)&Bt[kk][tn * 4];
      float a_[4] = {av.x, av.y, av.z, av.w};
      float b_[4] = {bv.x, bv.y, bv.z, bv.w};
#pragma unroll
      for (int i = 0; i < 4; i++)
#pragma unroll
        for (int j = 0; j < 4; j++) acc[i][j] = fmaf(a_[i], b_[j], acc[i][j]);
    }
  }
  float4 bb = *(const float4*)&bias[n0 + tn * 4];
  float bias_[4] = {bb.x, bb.y, bb.z, bb.w};
#pragma unroll
  for (int i = 0; i < 4; i++) {
    float4 o;
    o.x = acc[i][0] + bias_[0]; o.y = acc[i][1] + bias_[1];
    o.z = acc[i][2] + bias_[2]; o.w = acc[i][3] + bias_[3];
    *(float4*)(xz + ((size_t)tloc * 64 + tm * 4 + i) * Zdim + n0 + tn * 4) = o;
  }
}

// One WG (512 thr = 8 waves) per batch. LDS: h double-buffer (1 KB) + partial
// exchange (4 KB). W: 192 VGPRs resident + 16 uint4/step streamed from L2.
__global__ __launch_bounds__(512, 1) void lstm_chunk(
    const float* __restrict__ xz, const uint4* __restrict__ Wreg,
    const uint4* __restrict__ Wg, float* __restrict__ out,
    uint4* __restrict__ h_state, float* __restrict__ c_state,
    int t0, int Tc, int n_out) {
  __shared__ uint4 hq4[2][32];      // packed f16 h, double-buffered
  __shared__ float4 ppL[256];       // half=1 partial sums
  const int tid  = threadIdx.x;
  const int b    = blockIdx.x;
  const int half = tid >> 8, u = tid & 255;

  uint4 wr[4][QV];
#pragma unroll
  for (int g = 0; g < 4; g++)
#pragma unroll
    for (int j = 0; j < QV; j++)
      wr[g][j] = Wreg[(size_t)(g * QV + j) * 512 + tid];

  float c = 0.0f;
  if (t0 == 0) {
    if (tid < 64) ((uint4*)hq4)[tid] = make_uint4(0, 0, 0, 0);
  } else {
    if (tid < 32)  ((uint4*)hq4)[tid] = h_state[(size_t)b * 32 + tid];
    if (half == 0) c = c_state[(size_t)b * 256 + u];
  }
  __syncthreads();

  const float* xzb = xz + (size_t)b * Zdim + u;
  float nx0 = 0, nx1 = 0, nx2 = 0, nx3 = 0;
  if (half == 0) { nx0 = xzb[0]; nx1 = xzb[256]; nx2 = xzb[512]; nx3 = xzb[768]; }
  const uint4* wgt = Wg + tid;

  for (int tl = 0; tl < Tc; tl++) {
    const int buf = tl & 1;
    const uint4* hb = hq4[buf] + half * 16;
    float a0 = 0, a1 = 0, a2 = 0, a3 = 0;
    // batch 1 of streamed W (gates 0,1)
    uint4 l0 = wgt[0 * 512], l1 = wgt[1 * 512], l2 = wgt[2 * 512], l3 = wgt[3 * 512];
    uint4 l4 = wgt[4 * 512], l5 = wgt[5 * 512], l6 = wgt[6 * 512], l7 = wgt[7 * 512];
#pragma unroll
    for (int j = 0; j < QV; j++) {
      uint4 h4 = hb[j];
      a0 = dot4(wr[0][j], h4, a0);
      a1 = dot4(wr[1][j], h4, a1);
      a2 = dot4(wr[2][j], h4, a2);
      a3 = dot4(wr[3][j], h4, a3);
    }
    uint4 hg0 = hb[QV + 0], hg1 = hb[QV + 1], hg2 = hb[QV + 2], hg3 = hb[QV + 3];
    a0 = dot4(l0, hg0, a0); a0 = dot4(l1, hg1, a0); a0 = dot4(l2, hg2, a0); a0 = dot4(l3, hg3, a0);
    a1 = dot4(l4, hg0, a1); a1 = dot4(l5, hg1, a1); a1 = dot4(l6, hg2, a1); a1 = dot4(l7, hg3, a1);
    // batch 2 of streamed W (gates 2,3)
    uint4 m0 = wgt[8 * 512],  m1 = wgt[9 * 512],  m2 = wgt[10 * 512], m3 = wgt[11 * 512];
    uint4 m4 = wgt[12 * 512], m5 = wgt[13 * 512], m6 = wgt[14 * 512], m7 = wgt[15 * 512];
    a2 = dot4(m0, hg0, a2); a2 = dot4(m1, hg1, a2); a2 = dot4(m2, hg2, a2); a2 = dot4(m3, hg3, a2);
    a3 = dot4(m4, hg0, a3); a3 = dot4(m5, hg1, a3); a3 = dot4(m6, hg2, a3); a3 = dot4(m7, hg3, a3);

    if (half) ppL[u] = make_float4(a0, a1, a2, a3);
    __syncthreads();
    if (!half) {
      float4 pp = ppL[u];
      float z0 = a0 + pp.x + nx0, z1 = a1 + pp.y + nx1;
      float z2 = a2 + pp.z + nx2, z3 = a3 + pp.w + nx3;
      if (tl + 1 < Tc) {
        const float* xn = xzb + (size_t)(tl + 1) * (Bsz * Zdim);
        nx0 = xn[0]; nx1 = xn[256]; nx2 = xn[512]; nx3 = xn[768];
      }
      float ig = sigm(z0), fg = sigm(z1), gg = tanh_f(z2), og = sigm(z3);
      c = fg * c + ig * gg;
      float hn = og * tanh_f(c);
      int ot = (t0 + tl) - (Tsz - n_out);
      if (ot >= 0) out[((size_t)b * n_out + ot) * UNITSn + u] = hn;
      ((__half*)hq4[buf ^ 1])[u] = __float2half(hn);
    }
    __syncthreads();
  }
  if (tid < 32)  h_state[(size_t)b * 32 + tid] = ((uint4*)hq4)[(Tc & 1) * 32 + tid];
  if (half == 0) c_state[(size_t)b * 256 + u] = c;
}

extern "C" void kernel_launch(void* const* d_in, const int* in_sizes, int n_in,
                              void* d_out, int out_size, void* d_ws, size_t ws_size,
                              hipStream_t stream) {
  const float* x    = (const float*)d_in[0];
  const float* U    = (const float*)d_in[1];
  const float* W    = (const float*)d_in[2];
  const float* bias = (const float*)d_in[3];
  float* out = (float*)d_out;
  const int n_out = out_size / (Bsz * UNITSn);   // 32

  uint8_t* ws = (uint8_t*)d_ws;
  uint4* Wreg    = (uint4*)ws;                     // 384 KB
  uint4* Wg      = (uint4*)(ws + (384u << 10));    // 128 KB
  uint4* h_state = (uint4*)(ws + (512u << 10));    // 32 KB
  float* c_state = (float*)(ws + (544u << 10));    // 64 KB
  float* xz      = (float*)(ws + (1u << 20));      // Tc*64*1024 fp32

  int Tc = Tsz;
  while (Tc > 1 && (size_t)(1u << 20) + (size_t)Tc * (Bsz * Zdim) * 4 > ws_size) Tc >>= 1;

  convert_w2<<<dim3(128), dim3(256), 0, stream>>>(W, Wreg, Wg);

  for (int t0 = 0; t0 < Tsz; t0 += Tc) {
    proj_gemm<<<dim3(16, Tc), dim3(256), 0, stream>>>(x, U, bias, xz, t0);
    lstm_chunk<<<dim3(Bsz), dim3(512), 0, stream>>>(xz, Wreg, Wg, out, h_state,
                                                    c_state, t0, Tc, n_out);
  }
}